// Round 1
// baseline (645.947 us; speedup 1.0000x reference)
//
#include <hip/hip_runtime.h>

#define NHALF 4096
#define NROWS 8192
#define D 512
#define BM 128
#define BK 16
#define PAD 8
#define LDW (BM + PAD)   // 136 floats: 136*4=544 bytes, 16B-aligned rows

__device__ __forceinline__ const float* row_ptr(const float* __restrict__ src,
                                                const float* __restrict__ tgt, int r) {
    return (r < NHALF) ? (src + (size_t)r * D) : (tgt + (size_t)(r - NHALF) * D);
}

// --- Pass A1: per-row sum of squares + global sum of sq (for bandwidth) ---
__global__ void rowsq_kernel(const float* __restrict__ src, const float* __restrict__ tgt,
                             float* __restrict__ sq, double* __restrict__ sumsq) {
    int wave = threadIdx.x >> 6;
    int lane = threadIdx.x & 63;
    int r = blockIdx.x * 4 + wave;
    const float* p = row_ptr(src, tgt, r) + lane * 8;
    float4 v0 = *(const float4*)p;
    float4 v1 = *(const float4*)(p + 4);
    float s = v0.x*v0.x + v0.y*v0.y + v0.z*v0.z + v0.w*v0.w
            + v1.x*v1.x + v1.y*v1.y + v1.z*v1.z + v1.w*v1.w;
    for (int off = 32; off > 0; off >>= 1) s += __shfl_down(s, off);
    if (lane == 0) {
        sq[r] = s;
        atomicAdd(sumsq, (double)s);
    }
}

// --- Pass A2: column sums (for ||sum_i x_i||^2 term of sum(L2)) ---
__global__ void colsum_kernel(const float* __restrict__ src, const float* __restrict__ tgt,
                              float* __restrict__ colsum) {
    int c = threadIdx.x;             // 512 threads = 512 cols
    int r0 = blockIdx.x * 32;
    float acc = 0.f;
    for (int k = 0; k < 32; ++k) acc += row_ptr(src, tgt, r0 + k)[c];
    atomicAdd(&colsum[c], acc);
}

// --- Pass A3: bandwidth scalar ---
__global__ void bw_kernel(const float* __restrict__ colsum, const double* __restrict__ sumsq,
                          float* __restrict__ inv16bw) {
    __shared__ double red[512];
    int c = threadIdx.x;
    double v = (double)colsum[c];
    red[c] = v * v;
    __syncthreads();
    for (int s = 256; s > 0; s >>= 1) {
        if (c < s) red[c] += red[c + s];
        __syncthreads();
    }
    if (c == 0) {
        double m = (double)NROWS;
        double sumL2 = 2.0 * m * sumsq[0] - 2.0 * red[0];
        double bw = sumL2 / (m * m - m);
        bw = bw / 4.0;  // KERNEL_MUL ** (KERNEL_NUM//2) = 2^2
        inv16bw[0] = (float)(1.0 / (16.0 * bw));
    }
}

// --- Pass B: main pairwise kernel (upper-triangular blocks only) ---
__global__ __launch_bounds__(256)
void mmd_main(const float* __restrict__ src, const float* __restrict__ tgt,
              const float* __restrict__ sq, const float* __restrict__ inv16bw_p,
              double* __restrict__ S) {
    int bi = blockIdx.y, bj = blockIdx.x;
    if (bj < bi) return;   // symmetry: only bi<=bj, uniform per block

    __shared__ float As[BK][LDW];
    __shared__ float Bs[BK][LDW];

    int t  = threadIdx.x;
    int tx = t & 15, ty = t >> 4;

    float acc[8][8] = {};
    float inv16bw = inv16bw_p[0];

    int lr  = t >> 2;          // 0..63: row within tile (two passes: +0, +64)
    int lc4 = (t & 3) * 4;     // col offset within k-chunk

    const float* arow0 = row_ptr(src, tgt, bi * BM + lr)      + lc4;
    const float* arow1 = row_ptr(src, tgt, bi * BM + lr + 64) + lc4;
    const float* brow0 = row_ptr(src, tgt, bj * BM + lr)      + lc4;
    const float* brow1 = row_ptr(src, tgt, bj * BM + lr + 64) + lc4;

    for (int k0 = 0; k0 < D; k0 += BK) {
        float4 a0 = *(const float4*)(arow0 + k0);
        float4 a1 = *(const float4*)(arow1 + k0);
        float4 b0 = *(const float4*)(brow0 + k0);
        float4 b1 = *(const float4*)(brow1 + k0);
        __syncthreads();   // previous iteration's LDS reads done
        As[lc4+0][lr] = a0.x; As[lc4+1][lr] = a0.y; As[lc4+2][lr] = a0.z; As[lc4+3][lr] = a0.w;
        As[lc4+0][lr+64] = a1.x; As[lc4+1][lr+64] = a1.y; As[lc4+2][lr+64] = a1.z; As[lc4+3][lr+64] = a1.w;
        Bs[lc4+0][lr] = b0.x; Bs[lc4+1][lr] = b0.y; Bs[lc4+2][lr] = b0.z; Bs[lc4+3][lr] = b0.w;
        Bs[lc4+0][lr+64] = b1.x; Bs[lc4+1][lr+64] = b1.y; Bs[lc4+2][lr+64] = b1.z; Bs[lc4+3][lr+64] = b1.w;
        __syncthreads();
#pragma unroll
        for (int k = 0; k < BK; ++k) {
            float4 A0 = *(const float4*)&As[k][ty * 8];
            float4 A1 = *(const float4*)&As[k][ty * 8 + 4];
            float4 B0 = *(const float4*)&Bs[k][tx * 8];
            float4 B1 = *(const float4*)&Bs[k][tx * 8 + 4];
            float a[8] = {A0.x, A0.y, A0.z, A0.w, A1.x, A1.y, A1.z, A1.w};
            float b[8] = {B0.x, B0.y, B0.z, B0.w, B1.x, B1.y, B1.z, B1.w};
#pragma unroll
            for (int r = 0; r < 8; ++r)
#pragma unroll
                for (int c = 0; c < 8; ++c)
                    acc[r][c] += a[r] * b[c];
        }
    }

    // Epilogue: L2 -> 5-kernel sum via 1 exp + 4 squarings
    float sqi[8], sqj[8];
#pragma unroll
    for (int r = 0; r < 8; ++r) sqi[r] = sq[bi * BM + ty * 8 + r];
#pragma unroll
    for (int c = 0; c < 8; ++c) sqj[c] = sq[bj * BM + tx * 8 + c];

    float coef = ((bi == bj) ? 1.f : 2.f) * (((bi < 32) == (bj < 32)) ? 1.f : -1.f);

    float local = 0.f;
#pragma unroll
    for (int r = 0; r < 8; ++r) {
#pragma unroll
        for (int c = 0; c < 8; ++c) {
            float L2 = sqi[r] + sqj[c] - 2.f * acc[r][c];
            float u = __expf(-L2 * inv16bw);   // e^{-t/16}
            float ks = u;
            u *= u; ks += u;   // e^{-t/8}
            u *= u; ks += u;   // e^{-t/4}
            u *= u; ks += u;   // e^{-t/2}
            u *= u; ks += u;   // e^{-t}
            local += ks;
        }
    }
    local *= coef;

    for (int off = 32; off > 0; off >>= 1) local += __shfl_down(local, off);
    __shared__ float wsum[4];
    if ((t & 63) == 0) wsum[t >> 6] = local;
    __syncthreads();
    if (t == 0) {
        float b = wsum[0] + wsum[1] + wsum[2] + wsum[3];
        atomicAdd(S, (double)b);
    }
}

__global__ void finalize_kernel(const double* __restrict__ S, float* __restrict__ out) {
    out[0] = (float)(S[0] / ((double)NHALF * (double)NHALF));
}

extern "C" void kernel_launch(void* const* d_in, const int* in_sizes, int n_in,
                              void* d_out, int out_size, void* d_ws, size_t ws_size,
                              hipStream_t stream) {
    const float* src = (const float*)d_in[0];
    const float* tgt = (const float*)d_in[1];
    float* out = (float*)d_out;
    char* ws = (char*)d_ws;

    // ws layout
    float*  sq      = (float*)ws;                    // 8192 f32 = 32768 B
    float*  colsum  = (float*)(ws + 32768);          // 512 f32  = 2048 B
    double* sumsq   = (double*)(ws + 34816);         // 8 B
    double* S       = (double*)(ws + 34824);         // 8 B
    float*  inv16bw = (float*)(ws + 34832);          // 4 B

    // zero the accumulators (ws is poisoned 0xAA, not re-poisoned between replays)
    hipMemsetAsync(ws + 32768, 0, 2072, stream);

    rowsq_kernel<<<2048, 256, 0, stream>>>(src, tgt, sq, sumsq);
    colsum_kernel<<<256, 512, 0, stream>>>(src, tgt, colsum);
    bw_kernel<<<1, 512, 0, stream>>>(colsum, sumsq, inv16bw);
    mmd_main<<<dim3(64, 64), 256, 0, stream>>>(src, tgt, sq, inv16bw, S);
    finalize_kernel<<<1, 1, 0, stream>>>(S, out);
}

// Round 2
// 287.148 us; speedup vs baseline: 2.2495x; 2.2495x over previous
//
#include <hip/hip_runtime.h>

#define NHALF 4096
#define NROWS 8192
#define D 512
#define BM 128          // tile rows/cols
#define BK 64           // k-depth per LDS tile (bf16)
#define NB (NROWS / BM) // 64 block-rows
#define NTRI (NB * (NB + 1) / 2)  // 2080 upper-tri blocks

typedef __bf16 bf16x8 __attribute__((ext_vector_type(8)));
typedef float  f32x4  __attribute__((ext_vector_type(4)));

__device__ __forceinline__ const float* row_ptr(const float* __restrict__ src,
                                                const float* __restrict__ tgt, int r) {
    return (r < NHALF) ? (src + (size_t)r * D) : (tgt + (size_t)(r - NHALF) * D);
}

// --- Pass A1: per-row sum of squares + global sum (fp32 data, exact) ---
__global__ void rowsq_kernel(const float* __restrict__ src, const float* __restrict__ tgt,
                             float* __restrict__ sq, double* __restrict__ sumsq) {
    int wave = threadIdx.x >> 6;
    int lane = threadIdx.x & 63;
    int r = blockIdx.x * 4 + wave;
    const float* p = row_ptr(src, tgt, r) + lane * 8;
    float4 v0 = *(const float4*)p;
    float4 v1 = *(const float4*)(p + 4);
    float s = v0.x*v0.x + v0.y*v0.y + v0.z*v0.z + v0.w*v0.w
            + v1.x*v1.x + v1.y*v1.y + v1.z*v1.z + v1.w*v1.w;
    for (int off = 32; off > 0; off >>= 1) s += __shfl_down(s, off);
    if (lane == 0) {
        sq[r] = s;
        atomicAdd(sumsq, (double)s);
    }
}

// --- Pass A2: column sums ---
__global__ void colsum_kernel(const float* __restrict__ src, const float* __restrict__ tgt,
                              float* __restrict__ colsum) {
    int c = threadIdx.x;
    int r0 = blockIdx.x * 32;
    float acc = 0.f;
    for (int k = 0; k < 32; ++k) acc += row_ptr(src, tgt, r0 + k)[c];
    atomicAdd(&colsum[c], acc);
}

// --- Pass A3: bandwidth scalar ---
__global__ void bw_kernel(const float* __restrict__ colsum, const double* __restrict__ sumsq,
                          float* __restrict__ inv16bw) {
    __shared__ double red[512];
    int c = threadIdx.x;
    double v = (double)colsum[c];
    red[c] = v * v;
    __syncthreads();
    for (int s = 256; s > 0; s >>= 1) {
        if (c < s) red[c] += red[c + s];
        __syncthreads();
    }
    if (c == 0) {
        double m = (double)NROWS;
        double sumL2 = 2.0 * m * sumsq[0] - 2.0 * red[0];
        double bw = sumL2 / (m * m - m);
        bw = bw / 4.0;  // / KERNEL_MUL^(KERNEL_NUM//2)
        inv16bw[0] = (float)(1.0 / (16.0 * bw));
    }
}

// --- Pass B: MFMA pairwise kernel over upper-triangular blocks ---
__global__ __launch_bounds__(256)
void mmd_main(const float* __restrict__ src, const float* __restrict__ tgt,
              const float* __restrict__ sq, const float* __restrict__ inv16bw_p,
              double* __restrict__ S) {
    // XCD-aware swizzle (2080 % 8 == 0 -> bijective)
    int b = blockIdx.x;
    int ti = (b & 7) * (NTRI / 8) + (b >> 3);
    // map linear upper-tri index -> (bi, bj), bi <= bj
    int bi = (int)(64.5f - sqrtf(64.5f * 64.5f - 2.0f * (float)ti));
    while (bi * NB - bi * (bi - 1) / 2 > ti) --bi;
    while ((bi + 1) * NB - (bi + 1) * bi / 2 <= ti) ++bi;
    int bj = bi + (ti - (bi * NB - bi * (bi - 1) / 2));

    __shared__ __align__(16) __bf16 As[BM * BK];  // 16 KB, XOR-swizzled granules
    __shared__ __align__(16) __bf16 Bs[BM * BK];

    int t = threadIdx.x;
    int l = t & 63;
    int w = t >> 6;          // wave 0..3
    int wr = w >> 1, wc = w & 1;  // 2x2 wave grid, each wave 64x64 out
    int r0 = l & 15, kg = l >> 4;

    // staging coords: each thread stages half a row (32 floats) of A and B
    int srow = t >> 1;       // 0..127
    int half = t & 1;        // 0..1
    const float* arow = row_ptr(src, tgt, bi * BM + srow) + half * 32;
    const float* brow = row_ptr(src, tgt, bj * BM + srow) + half * 32;
    int sswz = srow & 7;

    f32x4 acc[4][4];
#pragma unroll
    for (int i = 0; i < 4; ++i)
#pragma unroll
        for (int j = 0; j < 4; ++j)
            acc[i][j] = (f32x4){0.f, 0.f, 0.f, 0.f};

    for (int k0 = 0; k0 < D; k0 += BK) {
        __syncthreads();   // previous iteration's LDS reads done
#pragma unroll
        for (int g = 0; g < 4; ++g) {
            float4 x = *(const float4*)(arow + k0 + g * 8);
            float4 y = *(const float4*)(arow + k0 + g * 8 + 4);
            bf16x8 v;
            v[0] = (__bf16)x.x; v[1] = (__bf16)x.y; v[2] = (__bf16)x.z; v[3] = (__bf16)x.w;
            v[4] = (__bf16)y.x; v[5] = (__bf16)y.y; v[6] = (__bf16)y.z; v[7] = (__bf16)y.w;
            int gr = (half * 4 + g) ^ sswz;
            *(bf16x8*)&As[srow * BK + gr * 8] = v;
        }
#pragma unroll
        for (int g = 0; g < 4; ++g) {
            float4 x = *(const float4*)(brow + k0 + g * 8);
            float4 y = *(const float4*)(brow + k0 + g * 8 + 4);
            bf16x8 v;
            v[0] = (__bf16)x.x; v[1] = (__bf16)x.y; v[2] = (__bf16)x.z; v[3] = (__bf16)x.w;
            v[4] = (__bf16)y.x; v[5] = (__bf16)y.y; v[6] = (__bf16)y.z; v[7] = (__bf16)y.w;
            int gr = (half * 4 + g) ^ sswz;
            *(bf16x8*)&Bs[srow * BK + gr * 8] = v;
        }
        __syncthreads();

#pragma unroll
        for (int ks = 0; ks < 2; ++ks) {
            bf16x8 af[4], bfr[4];
#pragma unroll
            for (int fi = 0; fi < 4; ++fi) {
                int row = wr * 64 + fi * 16 + r0;
                int gr = (ks * 4 + kg) ^ (row & 7);
                af[fi] = *(const bf16x8*)&As[row * BK + gr * 8];
            }
#pragma unroll
            for (int fj = 0; fj < 4; ++fj) {
                int row = wc * 64 + fj * 16 + r0;
                int gr = (ks * 4 + kg) ^ (row & 7);
                bfr[fj] = *(const bf16x8*)&Bs[row * BK + gr * 8];
            }
#pragma unroll
            for (int fi = 0; fi < 4; ++fi)
#pragma unroll
                for (int fj = 0; fj < 4; ++fj)
                    acc[fi][fj] = __builtin_amdgcn_mfma_f32_16x16x32_bf16(af[fi], bfr[fj], acc[fi][fj], 0, 0, 0);
        }
    }

    // Epilogue: L2 -> 5-kernel sum (1 exp + 4 squarings), signed block coef
    float inv16bw = inv16bw_p[0];
    float coef = ((bi == bj) ? 1.f : 2.f) * (((bi < NB / 2) == (bj < NB / 2)) ? 1.f : -1.f);

    float local = 0.f;
#pragma unroll
    for (int fi = 0; fi < 4; ++fi) {
#pragma unroll
        for (int fj = 0; fj < 4; ++fj) {
#pragma unroll
            for (int j = 0; j < 4; ++j) {
                int ig = bi * BM + wr * 64 + fi * 16 + (l >> 4) * 4 + j;
                int jg = bj * BM + wc * 64 + fj * 16 + (l & 15);
                float L2 = sq[ig] + sq[jg] - 2.f * acc[fi][fj][j];
                float u = __expf(-L2 * inv16bw);   // e^{-t/16}
                float ks = u;
                u *= u; ks += u;   // e^{-t/8}
                u *= u; ks += u;   // e^{-t/4}
                u *= u; ks += u;   // e^{-t/2}
                u *= u; ks += u;   // e^{-t}
                local += ks;
            }
        }
    }
    local *= coef;

    for (int off = 32; off > 0; off >>= 1) local += __shfl_down(local, off);
    __shared__ float wsum[4];
    if ((t & 63) == 0) wsum[t >> 6] = local;
    __syncthreads();
    if (t == 0) {
        float bsum = wsum[0] + wsum[1] + wsum[2] + wsum[3];
        atomicAdd(S, (double)bsum);
    }
}

__global__ void finalize_kernel(const double* __restrict__ S, float* __restrict__ out) {
    out[0] = (float)(S[0] / ((double)NHALF * (double)NHALF));
}

extern "C" void kernel_launch(void* const* d_in, const int* in_sizes, int n_in,
                              void* d_out, int out_size, void* d_ws, size_t ws_size,
                              hipStream_t stream) {
    const float* src = (const float*)d_in[0];
    const float* tgt = (const float*)d_in[1];
    float* out = (float*)d_out;
    char* ws = (char*)d_ws;

    float*  sq      = (float*)ws;                    // 8192 f32
    float*  colsum  = (float*)(ws + 32768);          // 512 f32
    double* sumsq   = (double*)(ws + 34816);
    double* S       = (double*)(ws + 34824);
    float*  inv16bw = (float*)(ws + 34832);

    hipMemsetAsync(ws + 32768, 0, 2072, stream);

    rowsq_kernel<<<2048, 256, 0, stream>>>(src, tgt, sq, sumsq);
    colsum_kernel<<<256, 512, 0, stream>>>(src, tgt, colsum);
    bw_kernel<<<1, 512, 0, stream>>>(colsum, sumsq, inv16bw);
    mmd_main<<<NTRI, 256, 0, stream>>>(src, tgt, sq, inv16bw, S);
    finalize_kernel<<<1, 1, 0, stream>>>(S, out);
}

// Round 5
// 98.002 us; speedup vs baseline: 6.5912x; 2.9300x over previous
//
#include <hip/hip_runtime.h>

#define NHALF 4096
#define NROWS 8192
#define D 512
#define BM 128
#define BK 64
#define NB (NROWS / BM)            // 64
#define NTRI (NB * (NB + 1) / 2)   // 2080

typedef __bf16 bf16x8 __attribute__((ext_vector_type(8)));
typedef float  f32x4  __attribute__((ext_vector_type(4)));

__device__ __forceinline__ const float* row_ptr(const float* __restrict__ src,
                                                const float* __restrict__ tgt, int r) {
    return (r < NHALF) ? (src + (size_t)r * D) : (tgt + (size_t)(r - NHALF) * D);
}

// --- Pass A: fused convert fp32->bf16 + rowsq + colsum + sumsq ---
// 128 blocks x 256 threads; block handles 64 rows, each wave 16 rows.
__global__ __launch_bounds__(256)
void conv_stats(const float* __restrict__ src, const float* __restrict__ tgt,
                __bf16* __restrict__ tot, float* __restrict__ sq,
                float* __restrict__ colsum, double* __restrict__ sumsq) {
    __shared__ float cs_lds[4][512];
    int t = threadIdx.x, l = t & 63, w = t >> 6;
    int rbase = blockIdx.x * 64 + w * 16;

    float cs[8] = {0.f, 0.f, 0.f, 0.f, 0.f, 0.f, 0.f, 0.f};
    float ssq = 0.f;

    for (int rr = 0; rr < 16; ++rr) {
        int r = rbase + rr;
        const float* p = row_ptr(src, tgt, r) + l * 8;
        float4 v0 = *(const float4*)p;
        float4 v1 = *(const float4*)(p + 4);
        bf16x8 o;
        o[0] = (__bf16)v0.x; o[1] = (__bf16)v0.y; o[2] = (__bf16)v0.z; o[3] = (__bf16)v0.w;
        o[4] = (__bf16)v1.x; o[5] = (__bf16)v1.y; o[6] = (__bf16)v1.z; o[7] = (__bf16)v1.w;
        *(bf16x8*)&tot[(size_t)r * D + l * 8] = o;
        float s8 = v0.x*v0.x + v0.y*v0.y + v0.z*v0.z + v0.w*v0.w
                 + v1.x*v1.x + v1.y*v1.y + v1.z*v1.z + v1.w*v1.w;
        ssq += s8;
        cs[0] += v0.x; cs[1] += v0.y; cs[2] += v0.z; cs[3] += v0.w;
        cs[4] += v1.x; cs[5] += v1.y; cs[6] += v1.z; cs[7] += v1.w;
        // row sum-of-squares
        float rsum = s8;
        for (int off = 32; off > 0; off >>= 1) rsum += __shfl_down(rsum, off);
        if (l == 0) sq[r] = rsum;
    }
    // colsum partials: wave -> LDS, then 2 cols per thread across 4 waves
#pragma unroll
    for (int j = 0; j < 8; ++j) cs_lds[w][l * 8 + j] = cs[j];
    // sumsq
    for (int off = 32; off > 0; off >>= 1) ssq += __shfl_down(ssq, off);
    __shared__ float wssq[4];
    if (l == 0) wssq[w] = ssq;
    __syncthreads();
    int c0 = t * 2;
    float a = cs_lds[0][c0] + cs_lds[1][c0] + cs_lds[2][c0] + cs_lds[3][c0];
    float b = cs_lds[0][c0+1] + cs_lds[1][c0+1] + cs_lds[2][c0+1] + cs_lds[3][c0+1];
    atomicAdd(&colsum[c0], a);
    atomicAdd(&colsum[c0 + 1], b);
    if (t == 0) atomicAdd(sumsq, (double)(wssq[0] + wssq[1] + wssq[2] + wssq[3]));
}

// --- Pass B: bandwidth scalar ---
__global__ void bw_kernel(const float* __restrict__ colsum, const double* __restrict__ sumsq,
                          float* __restrict__ inv16bw) {
    __shared__ double red[512];
    int c = threadIdx.x;
    double v = (double)colsum[c];
    red[c] = v * v;
    __syncthreads();
    for (int s = 256; s > 0; s >>= 1) {
        if (c < s) red[c] += red[c + s];
        __syncthreads();
    }
    if (c == 0) {
        double m = (double)NROWS;
        double sumL2 = 2.0 * m * sumsq[0] - 2.0 * red[0];
        double bw = sumL2 / (m * m - m);
        bw = bw / 4.0;  // / KERNEL_MUL^(KERNEL_NUM//2)
        inv16bw[0] = (float)(1.0 / (16.0 * bw));
    }
}

// --- Pass C: MFMA pairwise kernel, m97 structure + swizzled-source gload_lds ---
__global__ __launch_bounds__(256)
void mmd_main(const __bf16* __restrict__ tot,
              const float* __restrict__ sq, const float* __restrict__ inv16bw_p,
              double* __restrict__ S) {
    int b = blockIdx.x;
    int ti = (b & 7) * (NTRI / 8) + (b >> 3);   // XCD swizzle (2080 % 8 == 0)
    int bi = (int)(64.5f - sqrtf(64.5f * 64.5f - 2.0f * (float)ti));
    while (bi * NB - bi * (bi - 1) / 2 > ti) --bi;
    while ((bi + 1) * NB - (bi + 1) * bi / 2 <= ti) ++bi;
    int bj = bi + (ti - (bi * NB - bi * (bi - 1) / 2));

    __shared__ __align__(16) __bf16 As[BM * BK];  // 16 KB each, linear layout
    __shared__ __align__(16) __bf16 Bs[BM * BK];

    int t = threadIdx.x;
    int l = t & 63;
    int w = t >> 6;
    int wr = w >> 1, wc = w & 1;       // 2x2 wave grid, 64x64 out each
    int r0 = l & 15, kg = l >> 4;

    // staging: 16 segs of 8 rows; wave w owns segs w*4..w*4+3
    // source granule pre-swizzled so that swizzled ds_read sees correct data
    int srow_in_seg = l >> 3;                  // 0..7 == row&7
    int gsrc = (l & 7) ^ srow_in_seg;          // inverse swizzle on global source
    const __bf16* abase = tot + (size_t)(bi * BM) * D;
    const __bf16* bbase = tot + (size_t)(bj * BM) * D;

    f32x4 acc[4][4];
#pragma unroll
    for (int i = 0; i < 4; ++i)
#pragma unroll
        for (int j = 0; j < 4; ++j)
            acc[i][j] = (f32x4){0.f, 0.f, 0.f, 0.f};

    for (int k0 = 0; k0 < D; k0 += BK) {
        __syncthreads();   // previous iteration's LDS reads done
#pragma unroll
        for (int i = 0; i < 4; ++i) {
            int seg = w * 4 + i;
            int row = seg * 8 + srow_in_seg;
            __builtin_amdgcn_global_load_lds(
                (const __attribute__((address_space(1))) void*)(abase + (size_t)row * D + k0 + gsrc * 8),
                (__attribute__((address_space(3))) void*)(As + seg * 8 * BK),
                16, 0, 0);
            __builtin_amdgcn_global_load_lds(
                (const __attribute__((address_space(1))) void*)(bbase + (size_t)row * D + k0 + gsrc * 8),
                (__attribute__((address_space(3))) void*)(Bs + seg * 8 * BK),
                16, 0, 0);
        }
        __syncthreads();   // compiler drains vmcnt(0) before this barrier

#pragma unroll
        for (int ks = 0; ks < 2; ++ks) {
            bf16x8 af[4], bfr[4];
#pragma unroll
            for (int fi = 0; fi < 4; ++fi) {
                int row = wr * 64 + fi * 16 + r0;
                int g = (ks * 4 + kg) ^ (row & 7);
                af[fi] = *(const bf16x8*)&As[row * BK + g * 8];
            }
#pragma unroll
            for (int fj = 0; fj < 4; ++fj) {
                int row = wc * 64 + fj * 16 + r0;
                int g = (ks * 4 + kg) ^ (row & 7);
                bfr[fj] = *(const bf16x8*)&Bs[row * BK + g * 8];
            }
#pragma unroll
            for (int fi = 0; fi < 4; ++fi)
#pragma unroll
                for (int fj = 0; fj < 4; ++fj)
                    acc[fi][fj] = __builtin_amdgcn_mfma_f32_16x16x32_bf16(af[fi], bfr[fj], acc[fi][fj], 0, 0, 0);
        }
    }

    // Epilogue: L2 -> 5-kernel sum (1 exp + 4 squarings), signed block coef
    float inv16bw = inv16bw_p[0];
    float coef = ((bi == bj) ? 1.f : 2.f) * (((bi < NB / 2) == (bj < NB / 2)) ? 1.f : -1.f);

    float local = 0.f;
#pragma unroll
    for (int fi = 0; fi < 4; ++fi) {
#pragma unroll
        for (int fj = 0; fj < 4; ++fj) {
#pragma unroll
            for (int j = 0; j < 4; ++j) {
                int ig = bi * BM + wr * 64 + fi * 16 + (l >> 4) * 4 + j;
                int jg = bj * BM + wc * 64 + fj * 16 + (l & 15);
                float L2 = sq[ig] + sq[jg] - 2.f * acc[fi][fj][j];
                float u = __expf(-L2 * inv16bw);   // e^{-t/16}
                float ks = u;
                u *= u; ks += u;   // e^{-t/8}
                u *= u; ks += u;   // e^{-t/4}
                u *= u; ks += u;   // e^{-t/2}
                u *= u; ks += u;   // e^{-t}
                local += ks;
            }
        }
    }
    local *= coef;

    for (int off = 32; off > 0; off >>= 1) local += __shfl_down(local, off);
    __shared__ float wsum[4];
    if ((t & 63) == 0) wsum[t >> 6] = local;
    __syncthreads();
    if (t == 0) {
        float bsum = wsum[0] + wsum[1] + wsum[2] + wsum[3];
        atomicAdd(S, (double)bsum);
    }
}

__global__ void finalize_kernel(const double* __restrict__ S, float* __restrict__ out) {
    out[0] = (float)(S[0] / ((double)NHALF * (double)NHALF));
}

extern "C" void kernel_launch(void* const* d_in, const int* in_sizes, int n_in,
                              void* d_out, int out_size, void* d_ws, size_t ws_size,
                              hipStream_t stream) {
    const float* src = (const float*)d_in[0];
    const float* tgt = (const float*)d_in[1];
    float* out = (float*)d_out;
    char* ws = (char*)d_ws;

    // ws layout
    __bf16* tot     = (__bf16*)ws;                         // 8 MB  (8192*512*2)
    float*  sq      = (float*)(ws + 8388608);              // 32768 B
    float*  colsum  = (float*)(ws + 8388608 + 32768);      // 2048 B
    double* sumsq   = (double*)(ws + 8388608 + 34816);     // 8 B
    double* S       = (double*)(ws + 8388608 + 34824);     // 8 B
    float*  inv16bw = (float*)(ws + 8388608 + 34832);      // 4 B

    // zero accumulators (ws poisoned 0xAA, not re-poisoned between replays)
    hipMemsetAsync(ws + 8388608 + 32768, 0, 2068, stream);

    conv_stats<<<128, 256, 0, stream>>>(src, tgt, tot, sq, colsum, sumsq);
    bw_kernel<<<1, 512, 0, stream>>>(colsum, sumsq, inv16bw);
    mmd_main<<<NTRI, 256, 0, stream>>>(tot, sq, inv16bw, S);
    finalize_kernel<<<1, 1, 0, stream>>>(S, out);
}